// Round 10
// baseline (177.245 us; speedup 1.0000x reference)
//
#include <hip/hip_runtime.h>

typedef unsigned short ushort;
typedef unsigned int uint;
typedef unsigned char uchar;
typedef long long i64;
typedef __attribute__((ext_vector_type(4))) float floatx4;

// Problem constants
#define T_STEPS 100
#define BATCH   32
#define NIN     1024
#define NOUT    512

// K layout: k = b*SEG + t, t padded 100 -> 112. Operands stored fp8 e4m3,
// [rows][K], row stride 3648 B = 14.25 x 256B (rotates L2 channels).
#define SEG      112
#define KPAD     (BATCH * SEG)         // 3584 (GEMM K extent, bytes = elems)
#define KSTRIDEB 3648                  // row stride in bytes
#define KS       16
#define KCHUNK   (KPAD / KS)           // 224
#define BK       32

#define LR_LTP  (1e-4f)
#define LR_LTD  (-1e-4f)
#define INV_B   (1.0f / 32.0f)
#define DECAY   0.951229424500714f     // exp(-1/20)
#define D28     0.246596963941607f     // exp(-28/20)
#define TCH     28                     // t-chunk per thread
#define NCHUNK  4

// Output layout (floats): [delta_w | pre_tr_final | post_tr_final]
#define OFF_PRE  (NOUT * NIN)
#define OFF_POST (OFF_PRE + BATCH * NIN)

// Workspace (bytes): 4 fp8 operands, bf16 Spart slabs, tile counters
#define B_PRST  0
#define B_PRTT  ((size_t)NIN * KSTRIDEB)
#define B_POST  ((size_t)2 * NIN * KSTRIDEB)
#define B_POTT  ((size_t)2 * NIN * KSTRIDEB + (size_t)NOUT * KSTRIDEB)
#define B_END   ((size_t)2 * (NIN + NOUT) * KSTRIDEB)   // 11,206,656 B (16-aligned)
// bf16 partial slab stride: NOUT*NIN + 128 ushorts = 1,048,832 B = 4097 x 256B
#define SLABU   (NOUT * NIN + 128)
#define B_CNT   (B_END + (size_t)KS * SLABU * 2)        // 32 int tile counters
#define NTILES  ((NIN / 128) * (NOUT / 128))            // 32

static __device__ __forceinline__ uint pk4_fp8(float a, float b, float c, float d) {
    uint v = 0;
    v = __builtin_amdgcn_cvt_pk_fp8_f32(a, b, v, false);   // low 16 bits
    v = __builtin_amdgcn_cvt_pk_fp8_f32(c, d, v, true);    // high 16 bits
    return v;
}

static __device__ __forceinline__ ushort f2bf(float f) {
    union { float f; unsigned int u; } v; v.f = f;
    unsigned int r = (v.u + 0x7FFFu + ((v.u >> 16) & 1u)) >> 16;   // RNE
    return (ushort)r;
}

// ---------------------------------------------------------------------------
// Kernel A: trace recurrence fused with transpose, fp8 e4m3 outputs.
// (round 7's proven version + tile-counter zeroing)
// ---------------------------------------------------------------------------
__global__ __launch_bounds__(256) void stdp_traces_t(
    const float* __restrict__ pre_s,    // [T,B,NIN]
    const float* __restrict__ post_s,   // [T,B,NOUT]
    const float* __restrict__ pre_tr0,  // [B,NIN]
    const float* __restrict__ post_tr0, // [B,NOUT]
    uchar* __restrict__ pre_s_t, uchar* __restrict__ pre_tr_t,
    uchar* __restrict__ post_s_t, uchar* __restrict__ post_tr_t,
    int* __restrict__ cnt,
    float* __restrict__ out)
{
    __shared__ uint Ls[64 * 33];   // packed fp8 spikes, 8.25 KB
    __shared__ uint Lt[64 * 33];   // packed fp8 traces
    __shared__ float Eend[NCHUNK][64];

    // zero the gemm's tile-completion counters (stream-ordered before gemm)
    if (blockIdx.x == 0 && threadIdx.x < NTILES) cnt[threadIdx.x] = 0;

    const int chain = threadIdx.x & 63;
    const int c     = threadIdx.x >> 6;     // t-chunk, wave-uniform
    const int g     = blockIdx.x * 64 + chain;

    const float* src; const float* init;
    int id, stride, outoff;
    if (g < BATCH * NIN) {
        src = pre_s;  init = pre_tr0;
        id = g;               stride = BATCH * NIN;  outoff = OFF_PRE;
    } else {
        src = post_s; init = post_tr0;
        id = g - BATCH * NIN; stride = BATCH * NOUT; outoff = OFF_POST;
    }

    const int t0 = c * TCH;
    float x[TCH];
    #pragma unroll
    for (int m = 0; m < TCH; ++m)
        x[m] = (t0 + m < T_STEPS) ? src[(size_t)(t0 + m) * stride + id] : 0.f;

    // pack spikes to fp8 before the scan overwrites x[]
    uint sp[7];
    #pragma unroll
    for (int j = 0; j < 7; ++j)
        sp[j] = pk4_fp8(x[4*j], x[4*j+1], x[4*j+2], x[4*j+3]);

    // local scan (zero initial condition)
    float e = 0.f;
    #pragma unroll
    for (int m = 0; m < TCH; ++m) { e = e * DECAY + x[m]; x[m] = e; }
    Eend[c][chain] = e;
    __syncthreads();

    // carry into chunk c
    float C = init[id];
    for (int cc = 0; cc < c; ++cc) C = C * D28 + Eend[cc][chain];
    float p = C * DECAY;
    #pragma unroll
    for (int m = 0; m < TCH; ++m) { x[m] += p; p *= DECAY; }

    if (c == NCHUNK - 1) out[outoff + id] = x[15];   // t = 84 + 15 = 99

    // stage packed fp8 into LDS
    #pragma unroll
    for (int j = 0; j < 7; ++j) {
        const uint tj = pk4_fp8(x[4*j], x[4*j+1], x[4*j+2], x[4*j+3]);
        Ls[chain * 33 + c * 7 + j] = sp[j];
        Lt[chain * 33 + c * 7 + j] = tj;
    }
    __syncthreads();

    // cooperative coalesced write-out: 2 ops x 64 rows x 7 16B-chunks = 896
    const int id0 = blockIdx.x * 64;
    uchar *dS, *dT; int b0, ch0;
    if (id0 < BATCH * NIN) {
        b0 = id0 >> 10; ch0 = id0 & 1023; dS = pre_s_t;  dT = pre_tr_t;
    } else {
        const int idq = id0 - BATCH * NIN;
        b0 = idq >> 9;  ch0 = idq & 511;  dS = post_s_t; dT = post_tr_t;
    }
    #pragma unroll
    for (int j = 0; j < 4; ++j) {
        const int q = threadIdx.x + 256 * j;
        if (q < 896) {
            const int op = q >= 448;
            const int qq = q - op * 448;
            const int r  = qq / 7;
            const int cc = qq - r * 7;
            const uint* l = (op ? Lt : Ls) + r * 33 + cc * 4;
            const uint4 v = make_uint4(l[0], l[1], l[2], l[3]);
            uchar* gd = (op ? dT : dS) + (size_t)(ch0 + r) * KSTRIDEB + b0 * SEG + cc * 16;
            *(uint4*)gd = v;
        }
    }
}

// ---------------------------------------------------------------------------
// Kernel B: dual fp8 MFMA GEMM with fused K-reduction (threadfence pattern).
// 128x128 tile, BK=32, 4 waves 2x2, global_load_lds w=16, KS=16 (512 blocks
// = 2/CU, 7 K-iters).
//   P[o,i] = sum_k post_s[k,o]*pre_tr[k,i]
//   D[o,i] = sum_k post_tr[k,o]*pre_s[k,i]
// Each z-block stores bf16 slab Spart[z] = bf16(c1*(1-w)*P + c2*w*D), then
// threadfence + atomicAdd on its tile counter; the LAST z-block of each
// (x,y) tile sums all KS slab-tiles (L2-hot) and writes fp32 dw to out.
// ---------------------------------------------------------------------------
__global__ __launch_bounds__(256) void stdp_gemm_dual(
    const uchar* __restrict__ post_s_t, const uchar* __restrict__ pre_tr_t,
    const uchar* __restrict__ post_tr_t, const uchar* __restrict__ pre_s_t,
    const float* __restrict__ wmat, ushort* __restrict__ Spart,
    int* __restrict__ cnt, float* __restrict__ out)
{
    __shared__ uchar AsP[128 * 32];   // 4 KB each
    __shared__ uchar AsD[128 * 32];
    __shared__ uchar BsP[128 * 32];
    __shared__ uchar BsD[128 * 32];

    const int i0 = blockIdx.x * 128;
    const int o0 = blockIdx.y * 128;
    const int k0 = blockIdx.z * KCHUNK;

    const int tid  = threadIdx.x;
    const int w    = tid >> 6;
    const int lane = tid & 63;
    const int quad = lane >> 4;
    const int l16  = lane & 15;
    const int wm   = w & 1;
    const int wn   = w >> 1;

    floatx4 accP[4][4], accD[4][4];
    const floatx4 zero4 = {0.f, 0.f, 0.f, 0.f};
    #pragma unroll
    for (int mt = 0; mt < 4; ++mt)
        #pragma unroll
        for (int nt = 0; nt < 4; ++nt) { accP[mt][nt] = zero4; accD[mt][nt] = zero4; }

    for (int kb = k0; kb < k0 + KCHUNK; kb += BK) {
        // one 16B chunk per thread per operand: 256 chunks cover 128x32B
        {
            const int c   = w * 64 + lane;      // 0..255
            const int row = c >> 1;
            const int kob = (c & 1) * 16;
            const size_t aoff = (size_t)(o0 + row) * KSTRIDEB + kb + kob;
            const size_t boff = (size_t)(i0 + row) * KSTRIDEB + kb + kob;
            const int ldso = w * 1024;
            __builtin_amdgcn_global_load_lds(
                (const __attribute__((address_space(1))) void*)(post_s_t + aoff),
                (__attribute__((address_space(3))) void*)((char*)AsP + ldso), 16, 0, 0);
            __builtin_amdgcn_global_load_lds(
                (const __attribute__((address_space(1))) void*)(post_tr_t + aoff),
                (__attribute__((address_space(3))) void*)((char*)AsD + ldso), 16, 0, 0);
            __builtin_amdgcn_global_load_lds(
                (const __attribute__((address_space(1))) void*)(pre_tr_t + boff),
                (__attribute__((address_space(3))) void*)((char*)BsP + ldso), 16, 0, 0);
            __builtin_amdgcn_global_load_lds(
                (const __attribute__((address_space(1))) void*)(pre_s_t + boff),
                (__attribute__((address_space(3))) void*)((char*)BsD + ldso), 16, 0, 0);
        }
        __syncthreads();

        i64 aP[4], aD[4], bP[4], bD[4];
        #pragma unroll
        for (int mt = 0; mt < 4; ++mt) {
            const int r = (wm * 64 + mt * 16 + l16) * 32 + quad * 8;
            aP[mt] = *(const i64*)&AsP[r];
            aD[mt] = *(const i64*)&AsD[r];
        }
        #pragma unroll
        for (int nt = 0; nt < 4; ++nt) {
            const int r = (wn * 64 + nt * 16 + l16) * 32 + quad * 8;
            bP[nt] = *(const i64*)&BsP[r];
            bD[nt] = *(const i64*)&BsD[r];
        }
        #pragma unroll
        for (int mt = 0; mt < 4; ++mt)
            #pragma unroll
            for (int nt = 0; nt < 4; ++nt) {
                accP[mt][nt] = __builtin_amdgcn_mfma_f32_16x16x32_fp8_fp8(
                    aP[mt], bP[nt], accP[mt][nt], 0, 0, 0);
                accD[mt][nt] = __builtin_amdgcn_mfma_f32_16x16x32_fp8_fp8(
                    aD[mt], bD[nt], accD[mt][nt], 0, 0, 0);
            }
        __syncthreads();
    }

    // epilogue: C/D layout col = lane&15 (i), row = quad*4+reg (o)
    ushort* Sz = Spart + (size_t)blockIdx.z * SLABU;
    const float c1 = LR_LTP * INV_B;
    const float c2 = LR_LTD * INV_B;
    #pragma unroll
    for (int mt = 0; mt < 4; ++mt) {
        const int obase = o0 + wm * 64 + mt * 16 + quad * 4;
        #pragma unroll
        for (int nt = 0; nt < 4; ++nt) {
            const int i = i0 + wn * 64 + nt * 16 + l16;
            #pragma unroll
            for (int r = 0; r < 4; ++r) {
                const size_t idx = (size_t)(obase + r) * NIN + i;
                const float wv = wmat[idx];
                const float v = c1 * (1.0f - wv) * accP[mt][nt][r]
                              + c2 * wv          * accD[mt][nt][r];
                Sz[idx] = f2bf(v);
            }
        }
    }

    // fused K-reduction: last z-block of this tile sums all KS slabs
    __threadfence();
    __shared__ int lastFlag;
    if (tid == 0) {
        const int tile = blockIdx.y * (NIN / 128) + blockIdx.x;
        lastFlag = (atomicAdd(&cnt[tile], 1) == KS - 1);
    }
    __syncthreads();
    if (!lastFlag) return;
    __threadfence();   // acquire: make other blocks' slab stores visible

    // sum 16 slab-tiles (128x128 each) -> fp32 out. 2048 16B-chunks, 8/thread.
    #pragma unroll
    for (int gch = 0; gch < 8; ++gch) {
        const int q   = gch * 256 + tid;        // 0..2047
        const int row = q >> 4;                 // 0..127
        const int c16 = q & 15;                 // 16B chunk in 128-col span
        const size_t off = (size_t)(o0 + row) * NIN + i0 + c16 * 8;
        float s[8] = {0.f, 0.f, 0.f, 0.f, 0.f, 0.f, 0.f, 0.f};
        for (int z = 0; z < KS; ++z) {
            const uint4 v = *(const uint4*)(Spart + (size_t)z * SLABU + off);
            const uint u[4] = {v.x, v.y, v.z, v.w};
            #pragma unroll
            for (int qq = 0; qq < 4; ++qq) {
                union { uint u; float f; } lo, hi;
                lo.u = u[qq] << 16;
                hi.u = u[qq] & 0xFFFF0000u;
                s[2 * qq]     += lo.f;
                s[2 * qq + 1] += hi.f;
            }
        }
        float4* o = (float4*)(out + off);
        o[0] = make_float4(s[0], s[1], s[2], s[3]);
        o[1] = make_float4(s[4], s[5], s[6], s[7]);
    }
}

extern "C" void kernel_launch(void* const* d_in, const int* in_sizes, int n_in,
                              void* d_out, int out_size, void* d_ws, size_t ws_size,
                              hipStream_t stream) {
    const float* weight   = (const float*)d_in[0];
    const float* pre_s    = (const float*)d_in[1];
    const float* post_s   = (const float*)d_in[2];
    const float* pre_tr0  = (const float*)d_in[3];
    const float* post_tr0 = (const float*)d_in[4];
    float* out = (float*)d_out;

    uchar* wsb = (uchar*)d_ws;
    uchar* pre_s_t   = wsb + B_PRST;
    uchar* pre_tr_t  = wsb + B_PRTT;
    uchar* post_s_t  = wsb + B_POST;
    uchar* post_tr_t = wsb + B_POTT;
    ushort* Spart    = (ushort*)(wsb + B_END);
    int*    cnt      = (int*)(wsb + B_CNT);

    stdp_traces_t<<<dim3(BATCH * (NIN + NOUT) / 64), dim3(256), 0, stream>>>(
        pre_s, post_s, pre_tr0, post_tr0,
        pre_s_t, pre_tr_t, post_s_t, post_tr_t, cnt, out);

    stdp_gemm_dual<<<dim3(NIN / 128, NOUT / 128, KS), dim3(256), 0, stream>>>(
        post_s_t, pre_tr_t, post_tr_t, pre_s_t, weight, Spart, cnt, out);
}

// Round 11
// 100.058 us; speedup vs baseline: 1.7714x; 1.7714x over previous
//
#include <hip/hip_runtime.h>

typedef unsigned short ushort;
typedef unsigned int uint;
typedef unsigned char uchar;
typedef long long i64;
typedef __attribute__((ext_vector_type(4))) float floatx4;

// Problem constants
#define T_STEPS 100
#define BATCH   32
#define NIN     1024
#define NOUT    512

// K layout: k = b*SEG + t, t padded 100 -> 112. Operands stored fp8 e4m3,
// [rows][K], row stride 3648 B = 14.25 x 256B (rotates L2 channels).
#define SEG      112
#define KPAD     (BATCH * SEG)         // 3584 (GEMM K extent, bytes = elems)
#define KSTRIDEB 3648                  // row stride in bytes
#define KS       16
#define KCHUNK   (KPAD / KS)           // 224
#define BK       32

#define LR_LTP  (1e-4f)
#define LR_LTD  (-1e-4f)
#define INV_B   (1.0f / 32.0f)
#define DECAY   0.951229424500714f     // exp(-1/20)
#define D28     0.246596963941607f     // exp(-28/20)
#define TCH     28                     // t-chunk per thread
#define NCHUNK  4

// Output layout (floats): [delta_w | pre_tr_final | post_tr_final]
#define OFF_PRE  (NOUT * NIN)
#define OFF_POST (OFF_PRE + BATCH * NIN)

// Workspace (bytes): 4 fp8 operands, then bf16 Spart slabs
#define B_PRST  0
#define B_PRTT  ((size_t)NIN * KSTRIDEB)
#define B_POST  ((size_t)2 * NIN * KSTRIDEB)
#define B_POTT  ((size_t)2 * NIN * KSTRIDEB + (size_t)NOUT * KSTRIDEB)
#define B_END   ((size_t)2 * (NIN + NOUT) * KSTRIDEB)   // 11,206,656 B (16-aligned)
// bf16 partial slab stride: NOUT*NIN + 128 ushorts = 1,048,832 B = 4097 x 256B
// (odd 256B multiple -> full L2 channel rotation across slabs)
#define SLABU   (NOUT * NIN + 128)

// NOTE (hard-won, rounds 8+10): no device-scope atomics storms and no
// __threadfence-based cross-block reduction inside the hot kernels — both
// serialized the whole GPU (5-10x regressions). The 3-dispatch structure
// with streamed bf16 partial slabs is the proven optimum here.

static __device__ __forceinline__ uint pk4_fp8(float a, float b, float c, float d) {
    uint v = 0;
    v = __builtin_amdgcn_cvt_pk_fp8_f32(a, b, v, false);   // low 16 bits
    v = __builtin_amdgcn_cvt_pk_fp8_f32(c, d, v, true);    // high 16 bits
    return v;
}

static __device__ __forceinline__ ushort f2bf(float f) {
    union { float f; unsigned int u; } v; v.f = f;
    unsigned int r = (v.u + 0x7FFFu + ((v.u >> 16) & 1u)) >> 16;   // RNE
    return (ushort)r;
}

// ---------------------------------------------------------------------------
// Kernel A: trace recurrence fused with transpose, fp8 e4m3 outputs.
// Block = 64 chains x 4 t-chunks of 28 (t >= 100: spikes zero-padded).
// Split scan with exp(-28/20) carry fixup. fp8-packed results staged in LDS
// rows of 33 words, then written out cooperatively as 16B chunks.
// ---------------------------------------------------------------------------
__global__ __launch_bounds__(256) void stdp_traces_t(
    const float* __restrict__ pre_s,    // [T,B,NIN]
    const float* __restrict__ post_s,   // [T,B,NOUT]
    const float* __restrict__ pre_tr0,  // [B,NIN]
    const float* __restrict__ post_tr0, // [B,NOUT]
    uchar* __restrict__ pre_s_t, uchar* __restrict__ pre_tr_t,
    uchar* __restrict__ post_s_t, uchar* __restrict__ post_tr_t,
    float* __restrict__ out)
{
    __shared__ uint Ls[64 * 33];   // packed fp8 spikes, 8.25 KB
    __shared__ uint Lt[64 * 33];   // packed fp8 traces
    __shared__ float Eend[NCHUNK][64];

    const int chain = threadIdx.x & 63;
    const int c     = threadIdx.x >> 6;     // t-chunk, wave-uniform
    const int g     = blockIdx.x * 64 + chain;

    const float* src; const float* init;
    int id, stride, outoff;
    if (g < BATCH * NIN) {
        src = pre_s;  init = pre_tr0;
        id = g;               stride = BATCH * NIN;  outoff = OFF_PRE;
    } else {
        src = post_s; init = post_tr0;
        id = g - BATCH * NIN; stride = BATCH * NOUT; outoff = OFF_POST;
    }

    const int t0 = c * TCH;
    float x[TCH];
    #pragma unroll
    for (int m = 0; m < TCH; ++m)
        x[m] = (t0 + m < T_STEPS) ? src[(size_t)(t0 + m) * stride + id] : 0.f;

    // pack spikes to fp8 before the scan overwrites x[]
    uint sp[7];
    #pragma unroll
    for (int j = 0; j < 7; ++j)
        sp[j] = pk4_fp8(x[4*j], x[4*j+1], x[4*j+2], x[4*j+3]);

    // local scan (zero initial condition)
    float e = 0.f;
    #pragma unroll
    for (int m = 0; m < TCH; ++m) { e = e * DECAY + x[m]; x[m] = e; }
    Eend[c][chain] = e;
    __syncthreads();

    // carry into chunk c
    float C = init[id];
    for (int cc = 0; cc < c; ++cc) C = C * D28 + Eend[cc][chain];
    float p = C * DECAY;
    #pragma unroll
    for (int m = 0; m < TCH; ++m) { x[m] += p; p *= DECAY; }

    if (c == NCHUNK - 1) out[outoff + id] = x[15];   // t = 84 + 15 = 99

    // stage packed fp8 into LDS
    #pragma unroll
    for (int j = 0; j < 7; ++j) {
        const uint tj = pk4_fp8(x[4*j], x[4*j+1], x[4*j+2], x[4*j+3]);
        Ls[chain * 33 + c * 7 + j] = sp[j];
        Lt[chain * 33 + c * 7 + j] = tj;
    }
    __syncthreads();

    // cooperative coalesced write-out: 2 ops x 64 rows x 7 16B-chunks = 896
    const int id0 = blockIdx.x * 64;
    uchar *dS, *dT; int b0, ch0;
    if (id0 < BATCH * NIN) {
        b0 = id0 >> 10; ch0 = id0 & 1023; dS = pre_s_t;  dT = pre_tr_t;
    } else {
        const int idq = id0 - BATCH * NIN;
        b0 = idq >> 9;  ch0 = idq & 511;  dS = post_s_t; dT = post_tr_t;
    }
    #pragma unroll
    for (int j = 0; j < 4; ++j) {
        const int q = threadIdx.x + 256 * j;
        if (q < 896) {
            const int op = q >= 448;
            const int qq = q - op * 448;
            const int r  = qq / 7;
            const int cc = qq - r * 7;
            const uint* l = (op ? Lt : Ls) + r * 33 + cc * 4;
            const uint4 v = make_uint4(l[0], l[1], l[2], l[3]);
            uchar* gd = (op ? dT : dS) + (size_t)(ch0 + r) * KSTRIDEB + b0 * SEG + cc * 16;
            *(uint4*)gd = v;
        }
    }
}

// ---------------------------------------------------------------------------
// Kernel B: dual fp8 MFMA GEMM, 128x128 tile, BK=32, 4 waves 2x2,
// global_load_lds w=16, KS=16 K-split (512 blocks = 2/CU, 7 K-iters).
//   P[o,i] = sum_k post_s[k,o]*pre_tr[k,i]
//   D[o,i] = sum_k post_tr[k,o]*pre_s[k,i]
// Epilogue pre-combines with w and stores BF16 partials:
//   Spart[z][o,i] = bf16( c1*(1-w)*P + c2*w*D )
// Grid (8,4,16) x-fastest: with round-robin block->XCD dispatch, all blocks
// sharing a B-slab (same x) land on one XCD -> B stays in that L2. Keep.
// ---------------------------------------------------------------------------
__global__ __launch_bounds__(256) void stdp_gemm_dual(
    const uchar* __restrict__ post_s_t, const uchar* __restrict__ pre_tr_t,
    const uchar* __restrict__ post_tr_t, const uchar* __restrict__ pre_s_t,
    const float* __restrict__ wmat, ushort* __restrict__ Spart)
{
    __shared__ uchar AsP[128 * 32];   // 4 KB each
    __shared__ uchar AsD[128 * 32];
    __shared__ uchar BsP[128 * 32];
    __shared__ uchar BsD[128 * 32];

    const int i0 = blockIdx.x * 128;
    const int o0 = blockIdx.y * 128;
    const int k0 = blockIdx.z * KCHUNK;

    const int tid  = threadIdx.x;
    const int w    = tid >> 6;
    const int lane = tid & 63;
    const int quad = lane >> 4;
    const int l16  = lane & 15;
    const int wm   = w & 1;
    const int wn   = w >> 1;

    floatx4 accP[4][4], accD[4][4];
    const floatx4 zero4 = {0.f, 0.f, 0.f, 0.f};
    #pragma unroll
    for (int mt = 0; mt < 4; ++mt)
        #pragma unroll
        for (int nt = 0; nt < 4; ++nt) { accP[mt][nt] = zero4; accD[mt][nt] = zero4; }

    for (int kb = k0; kb < k0 + KCHUNK; kb += BK) {
        // one 16B chunk per thread per operand: 256 chunks cover 128x32B
        {
            const int c   = w * 64 + lane;      // 0..255
            const int row = c >> 1;
            const int kob = (c & 1) * 16;
            const size_t aoff = (size_t)(o0 + row) * KSTRIDEB + kb + kob;
            const size_t boff = (size_t)(i0 + row) * KSTRIDEB + kb + kob;
            const int ldso = w * 1024;
            __builtin_amdgcn_global_load_lds(
                (const __attribute__((address_space(1))) void*)(post_s_t + aoff),
                (__attribute__((address_space(3))) void*)((char*)AsP + ldso), 16, 0, 0);
            __builtin_amdgcn_global_load_lds(
                (const __attribute__((address_space(1))) void*)(post_tr_t + aoff),
                (__attribute__((address_space(3))) void*)((char*)AsD + ldso), 16, 0, 0);
            __builtin_amdgcn_global_load_lds(
                (const __attribute__((address_space(1))) void*)(pre_tr_t + boff),
                (__attribute__((address_space(3))) void*)((char*)BsP + ldso), 16, 0, 0);
            __builtin_amdgcn_global_load_lds(
                (const __attribute__((address_space(1))) void*)(pre_s_t + boff),
                (__attribute__((address_space(3))) void*)((char*)BsD + ldso), 16, 0, 0);
        }
        __syncthreads();

        i64 aP[4], aD[4], bP[4], bD[4];
        #pragma unroll
        for (int mt = 0; mt < 4; ++mt) {
            const int r = (wm * 64 + mt * 16 + l16) * 32 + quad * 8;
            aP[mt] = *(const i64*)&AsP[r];
            aD[mt] = *(const i64*)&AsD[r];
        }
        #pragma unroll
        for (int nt = 0; nt < 4; ++nt) {
            const int r = (wn * 64 + nt * 16 + l16) * 32 + quad * 8;
            bP[nt] = *(const i64*)&BsP[r];
            bD[nt] = *(const i64*)&BsD[r];
        }
        #pragma unroll
        for (int mt = 0; mt < 4; ++mt)
            #pragma unroll
            for (int nt = 0; nt < 4; ++nt) {
                accP[mt][nt] = __builtin_amdgcn_mfma_f32_16x16x32_fp8_fp8(
                    aP[mt], bP[nt], accP[mt][nt], 0, 0, 0);
                accD[mt][nt] = __builtin_amdgcn_mfma_f32_16x16x32_fp8_fp8(
                    aD[mt], bD[nt], accD[mt][nt], 0, 0, 0);
            }
        __syncthreads();
    }

    // epilogue: C/D layout col = lane&15 (i), row = quad*4+reg (o)
    ushort* Sz = Spart + (size_t)blockIdx.z * SLABU;
    const float c1 = LR_LTP * INV_B;
    const float c2 = LR_LTD * INV_B;
    #pragma unroll
    for (int mt = 0; mt < 4; ++mt) {
        const int obase = o0 + wm * 64 + mt * 16 + quad * 4;
        #pragma unroll
        for (int nt = 0; nt < 4; ++nt) {
            const int i = i0 + wn * 64 + nt * 16 + l16;
            #pragma unroll
            for (int r = 0; r < 4; ++r) {
                const size_t idx = (size_t)(obase + r) * NIN + i;
                const float wv = wmat[idx];
                const float v = c1 * (1.0f - wv) * accP[mt][nt][r]
                              + c2 * wv          * accD[mt][nt][r];
                Sz[idx] = f2bf(v);
            }
        }
    }
}

// ---------------------------------------------------------------------------
// Kernel C: sum the KS bf16 slabs -> fp32 dw. One thread per 8 outputs
// (16B slab loads), fp32 accumulation via bit-unpack.
// 512 blocks x 128 threads (2 blocks/CU) to cover the 16-load latency chains.
// ---------------------------------------------------------------------------
__global__ __launch_bounds__(128) void stdp_finalize(
    const ushort* __restrict__ Spart, float* __restrict__ out)
{
    const int j = blockIdx.x * blockDim.x + threadIdx.x;   // 8-element group
    float s[8] = {0.f, 0.f, 0.f, 0.f, 0.f, 0.f, 0.f, 0.f};
    #pragma unroll
    for (int z = 0; z < KS; ++z) {
        const uint4 v = *(const uint4*)(Spart + (size_t)z * SLABU + (size_t)j * 8);
        const uint u[4] = {v.x, v.y, v.z, v.w};
        #pragma unroll
        for (int q = 0; q < 4; ++q) {
            union { uint u; float f; } lo, hi;
            lo.u = u[q] << 16;
            hi.u = u[q] & 0xFFFF0000u;
            s[2 * q]     += lo.f;
            s[2 * q + 1] += hi.f;
        }
    }
    float4* o = (float4*)(out + (size_t)j * 8);
    o[0] = make_float4(s[0], s[1], s[2], s[3]);
    o[1] = make_float4(s[4], s[5], s[6], s[7]);
}

extern "C" void kernel_launch(void* const* d_in, const int* in_sizes, int n_in,
                              void* d_out, int out_size, void* d_ws, size_t ws_size,
                              hipStream_t stream) {
    const float* weight   = (const float*)d_in[0];
    const float* pre_s    = (const float*)d_in[1];
    const float* post_s   = (const float*)d_in[2];
    const float* pre_tr0  = (const float*)d_in[3];
    const float* post_tr0 = (const float*)d_in[4];
    float* out = (float*)d_out;

    uchar* wsb = (uchar*)d_ws;
    uchar* pre_s_t   = wsb + B_PRST;
    uchar* pre_tr_t  = wsb + B_PRTT;
    uchar* post_s_t  = wsb + B_POST;
    uchar* post_tr_t = wsb + B_POTT;
    ushort* Spart    = (ushort*)(wsb + B_END);

    stdp_traces_t<<<dim3(BATCH * (NIN + NOUT) / 64), dim3(256), 0, stream>>>(
        pre_s, post_s, pre_tr0, post_tr0,
        pre_s_t, pre_tr_t, post_s_t, post_tr_t, out);

    stdp_gemm_dual<<<dim3(NIN / 128, NOUT / 128, KS), dim3(256), 0, stream>>>(
        post_s_t, pre_tr_t, post_tr_t, pre_s_t, weight, Spart);

    stdp_finalize<<<dim3((NOUT * NIN / 8) / 128), dim3(128), 0, stream>>>(
        Spart, out);
}